// Round 2
// baseline (205.967 us; speedup 1.0000x reference)
//
#include <hip/hip_runtime.h>
#include <stdint.h>

// CycleFC 1w1a: out[b,o,h,w] = sum_c sign(x)[b,c,h,w+off(c)] * sign(W)[o,c] + bias[o]
// off(c) = (c+3)%7 - 3, zero-pad OOB. B=64, C=O=384, H=W=32.
//
// Binary-GEMM: pack signs (bit=1 iff <0) into 6 u64 words; out = bias2 - 2*popc(G^WB).
// bias2t[w][o] = bias[o] + Nvalid(w) + 2*popc(WB & ~V(w)) precomputed in prep.
//
// R7: R6 split bought ~0 (pack+gemm ~= fused 71us under constant-overhead model).
// Two algorithmic cuts, then re-fuse:
//  (1) apply the cycle shift PRE-transpose: lane holds channel c's 32 w-bits,
//      g = myw >> off (or << -off); logical-shift zero-fill IS the OOB zero-pad.
//      Deletes the whole neighbor-OR phase (Pm masks, LDS X, 7 ORs/word).
//  (2) 32x32 bit-transpose in registers: 5-step shfl_xor butterfly per 32-lane
//      half (~40 VALU) instead of 32 ballots + 32 serialized lane0 ds_writes.
// One kernel, 6 waves/block, 2 rows/block, ONE barrier, 3KB LDS, grid 1024.
// popc-GEMM loop + wbg/bias2t formats identical to the R5-proven path.

#define IN_CH 384
#define HH 32
#define WW 32
#define BB 64

constexpr uint64_t P7(int t) {
  uint64_t m = 0;
  for (int k = 0; k < 64; ++k)
    if (k % 7 == t) m |= (1ull << k);
  return m;
}
__device__ __constant__ uint64_t Pm[7] = {P7(0), P7(1), P7(2), P7(3), P7(4), P7(5), P7(6)};

// ---------------- prep: one block (1 wave) per output channel o --------------
__global__ __launch_bounds__(64) void cyc_prep(const float* __restrict__ wgt,
                                               const float* __restrict__ bias,
                                               uint64_t* __restrict__ wbg,
                                               float* __restrict__ bias2t) {
  const int o = blockIdx.x;
  const int lane = threadIdx.x;
  __shared__ uint64_t wb_sh[6];
#pragma unroll
  for (int j = 0; j < 6; ++j) {
    uint64_t m = __ballot(wgt[o * IN_CH + j * 64 + lane] < 0.0f);
    if (lane == 0) wb_sh[j] = m;
  }
  __syncthreads();
  if (lane < 6) wbg[o * 6 + lane] = wb_sh[lane];
  if (lane < WW) {
    const int w = lane;
    int nv = 0, corr = 0;
#pragma unroll
    for (int j = 0; j < 6; ++j) {
      uint64_t V = 0;
#pragma unroll
      for (int d = -3; d <= 3; ++d) {
        int wd = w + d;
        if (wd >= 0 && wd < WW) V |= Pm[(d - j + 14) % 7];
      }
      nv += __popcll(V);
      corr += __popcll(wb_sh[j] & ~V);
    }
    // layout [w][o]: phase-2 lanes load 32 contiguous floats per half
    bias2t[w * IN_CH + o] = bias[o] + (float)nv + 2.0f * (float)corr;
  }
}

// ---------------- fused main: block = (b, 2 rows), 384 thr = 6 waves ---------
__global__ __launch_bounds__(384, 4) void cyc_fused(const float* __restrict__ x,
                                                    const uint64_t* __restrict__ wbg,
                                                    const float* __restrict__ bias2t,
                                                    float* __restrict__ out) {
  // sh_G[k][r][w]: u32 word k=2j+h holds channels j*64+h*32+0..31, pixel (r,w)
  __shared__ uint32_t sh_G[12][2][WW];  // 3072 B
  const int t = threadIdx.x;
  const int b = blockIdx.x >> 4;
  const int h0 = (blockIdx.x & 15) * 2;
  const int wave = t >> 6, lane = t & 63;

  // ---- pack phase: wave j handles channels c = j*64 + lane, rows h0, h0+1.
  {
    const int j = wave;
    const int c = j * 64 + lane;
    const int cm = c % 7;
    const int off = ((cm + 3) % 7) - 3;  // in [-3,3]
    const uint32_t shr = (off > 0) ? (uint32_t)off : 0u;
    const uint32_t shl = (off < 0) ? (uint32_t)(-off) : 0u;
#pragma unroll
    for (int r = 0; r < 2; ++r) {
      const float4* xp = reinterpret_cast<const float4*>(
          x + (size_t)((b * IN_CH + c) * HH + h0 + r) * WW);
      uint32_t myw = 0;
#pragma unroll
      for (int i = 0; i < 8; ++i) {
        float4 v = xp[i];
        myw |= (v.x < 0.0f ? 1u : 0u) << (i * 4 + 0);
        myw |= (v.y < 0.0f ? 1u : 0u) << (i * 4 + 1);
        myw |= (v.z < 0.0f ? 1u : 0u) << (i * 4 + 2);
        myw |= (v.w < 0.0f ? 1u : 0u) << (i * 4 + 3);
      }
      // pre-transpose cycle shift: bit w := myw bit (w+off), zero-fill == OOB pad
      uint32_t s = (myw >> shr) << shl;  // one of shr/shl is 0
      // 5-step 32x32 bit transpose across each 32-lane half.
      // After: lane (h = lane>>5, w = lane&31) holds bit k = shifted sign of
      // channel j*64 + h*32 + k at pixel w.
      constexpr uint32_t Mt[5] = {0xFFFF0000u, 0xFF00FF00u, 0xF0F0F0F0u,
                                  0xCCCCCCCCu, 0xAAAAAAAAu};
#pragma unroll
      for (int stp = 0; stp < 5; ++stp) {
        const int js = 16 >> stp;
        const uint32_t M = Mt[stp];
        uint32_t y = __shfl_xor(s, js);
        s = (lane & js) ? ((s & M) | ((y >> js) & ~M))
                        : ((s & ~M) | ((y << js) & M));
      }
      sh_G[2 * j + (lane >> 5)][r][lane & 31] = s;
    }
  }
  __syncthreads();

  // ---- gemm phase: wave og owns 64 output channels; lane = (r2, w) pixel.
  const int og = __builtin_amdgcn_readfirstlane(wave);
  const int w = lane & 31, r2 = lane >> 5;
  uint64_t g[6];
#pragma unroll
  for (int jj = 0; jj < 6; ++jj) {
    uint32_t lo = sh_G[2 * jj + 0][r2][w];
    uint32_t hi = sh_G[2 * jj + 1][r2][w];
    g[jj] = ((uint64_t)hi << 32) | (uint64_t)lo;
  }
#pragma unroll
  for (int half = 0; half < 2; ++half) {
    const int ob = og * 64 + half * 32;
    float bb[32];
    {
      const float4* bsrc =
          reinterpret_cast<const float4*>(bias2t + w * IN_CH + ob);
      float4* bdst = reinterpret_cast<float4*>(bb);
#pragma unroll
      for (int i = 0; i < 8; ++i) bdst[i] = bsrc[i];
    }
    const uint64_t* wp = wbg + (size_t)ob * 6;
    // lanes cover (h0+r2)*32+w = h0*32+lane -> 256B contiguous store per o
    float* op = out + ((size_t)b * IN_CH + ob) * (HH * WW) + h0 * WW + lane;
#pragma unroll
    for (int i = 0; i < 32; ++i) {
      const uint64_t w0 = wp[i * 6 + 0], w1 = wp[i * 6 + 1], w2 = wp[i * 6 + 2];
      const uint64_t w3 = wp[i * 6 + 3], w4 = wp[i * 6 + 4], w5 = wp[i * 6 + 5];
      int mm = __popcll(g[0] ^ w0) + __popcll(g[1] ^ w1) + __popcll(g[2] ^ w2) +
               __popcll(g[3] ^ w3) + __popcll(g[4] ^ w4) + __popcll(g[5] ^ w5);
      op[i * (HH * WW)] = bb[i] - 2.0f * (float)mm;
    }
  }
}

extern "C" void kernel_launch(void* const* d_in, const int* in_sizes, int n_in,
                              void* d_out, int out_size, void* d_ws, size_t ws_size,
                              hipStream_t stream) {
  const float* x = (const float*)d_in[0];
  const float* wgt = (const float*)d_in[1];
  const float* bias = (const float*)d_in[2];
  float* out = (float*)d_out;

  // ws layout: wbg @ 0 (18432 B), bias2t @ 18432 (49152 B)
  uint64_t* wbg = (uint64_t*)d_ws;
  float* bias2t = (float*)((char*)d_ws + 18432);

  cyc_prep<<<IN_CH, 64, 0, stream>>>(wgt, bias, wbg, bias2t);
  cyc_fused<<<BB * (HH / 2), 384, 0, stream>>>(x, wbg, bias2t, out);
}